// Round 15
// baseline (311.713 us; speedup 1.0000x reference)
//
#include <hip/hip_runtime.h>
#include <math.h>

#define N1c 10000
#define N2c 10000
#define F_INc 256
#define Ec 480000
#define Pc 200000
#define Lc 2
#define NPART 32
#define NPc 313    // ceil(10000/32)
#define NBLK 256   // chunks per edge structure
#define CAPE 17408 // per-partition staging capacity, edges
#define CAPP 7936  // per-partition staging capacity, pairs

using short8 = __attribute__((ext_vector_type(8))) short;
using float4v = __attribute__((ext_vector_type(4))) float;
using floatx2 = __attribute__((ext_vector_type(2))) float;

__device__ __forceinline__ float gelu_f(float x) {
    const float k0 = 0.7978845608028654f;
    const float k1 = 0.044715f;
    float x3 = x * x * x;
    float t = tanhf(k0 * (x + k1 * x3));
    return 0.5f * x * (1.0f + t);
}

__device__ __forceinline__ float bf2f(unsigned short x) {
    union { unsigned int u; float f; } c;
    c.u = ((unsigned int)x) << 16;
    return c.f;
}
__device__ __forceinline__ unsigned short f2bf(float f) {
    union { float f; unsigned int u; } c;
    c.f = f;
    unsigned int u = c.u;
    unsigned int r = (u + 0x7FFFu + ((u >> 16) & 1u)) >> 16;
    return (unsigned short)r;
}
__device__ __forceinline__ unsigned char f2fp8(float v) {
    unsigned int p = __builtin_amdgcn_cvt_pk_fp8_f32(v, v, 0u, false);
    return (unsigned char)(p & 0xFF);
}

// ---------------- merged weight prep (also zeroes gcnt) ----------------
__global__ __launch_bounds__(256) void prep_kernel(
    const float* __restrict__ Wq, const float* __restrict__ bq,
    const float* __restrict__ Wk, const float* __restrict__ bk,
    const float* __restrict__ Wv, const float* __restrict__ bv,
    const float* __restrict__ arel, const float* __restrict__ mrel,
    const float* __restrict__ prior,
    const float* __restrict__ Win1, const float* __restrict__ Win2,
    const float* __restrict__ Wa,
    short* __restrict__ Wqkvt, float* __restrict__ bqkv,
    short* __restrict__ Wint1, short* __restrict__ Wint2, short* __restrict__ Wat,
    int* __restrict__ gcnt)
{
    if (blockIdx.x == 0 && threadIdx.x < 3 * NPART) gcnt[threadIdx.x] = 0;
    int id = blockIdx.x * 256 + threadIdx.x;
    if (id < 196608) {
        int lt = id / 49152;
        int r = id - lt * 49152;
        int col = r >> 7, c = r & 127;
        short* Wout = Wqkvt + (size_t)lt * 384 * 128;
        float* bout = bqkv + lt * 384;
        if (col < 128) {
            Wout[col * 128 + c] = (short)f2bf(Wq[lt * 16384 + c * 128 + col]);
            if (c == 0) bout[col] = bq[lt * 128 + col];
            return;
        }
        int which = (col < 256) ? 0 : 1;
        int he = col - (which ? 256 : 128);
        int h = he >> 4, e = he & 15;
        const float* W = (which == 0 ? Wk : Wv) + lt * 16384;
        const float* b = (which == 0 ? bk : bv) + lt * 128;
        const float* R = (which == 0 ? arel : mrel) + lt * 2048;
        float sc = (which == 0) ? prior[lt * 8 + h] * 0.25f : 1.0f;
        float acc = 0.f;
        #pragma unroll
        for (int d = 0; d < 16; d++)
            acc += W[c * 128 + h * 16 + d] * R[(h * 16 + d) * 16 + e];
        Wout[col * 128 + c] = (short)f2bf(acc * sc);
        if (c == 0) {
            float bacc = 0.f;
            #pragma unroll
            for (int d = 0; d < 16; d++)
                bacc += b[h * 16 + d] * R[(h * 16 + d) * 16 + e];
            bout[col] = bacc * sc;
        }
    } else {
        int wid = id - 196608;
        if (wid < 65536) {
            int y = wid >> 15;
            int id2 = wid & 32767;
            int n = id2 >> 8, k = id2 & 255;
            const float* W = y ? Win2 : Win1;
            short* O = y ? Wint2 : Wint1;
            O[n * 256 + k] = (short)f2bf(W[k * 128 + n]);
        } else {
            int wid2 = wid - 65536;
            int lt = wid2 >> 14;
            int id2 = wid2 & 16383;
            int n = id2 >> 7, k = id2 & 127;
            Wat[lt * 16384 + n * 128 + k] = (short)f2bf(Wa[lt * 16384 + k * 128 + n]);
        }
    }
}

// ---------------- CSR: single-pass binning + build ----------------
__global__ __launch_bounds__(256) void scatter_bins_kernel(
    const int* __restrict__ ei12, const int* __restrict__ ei21, const int* __restrict__ eidx,
    int* __restrict__ gcnt,
    unsigned int* __restrict__ stg12, unsigned int* __restrict__ stg21,
    unsigned int* __restrict__ stgm)
{
    int blk = blockIdx.x, z = blockIdx.y, t = threadIdx.x;
    const int* key; const int* pay; int E; unsigned int* stg; int cap;
    if (z == 0)      { key = ei12 + Ec; pay = ei12; E = Ec; stg = stg12; cap = CAPE; }
    else if (z == 1) { key = ei21 + Ec; pay = ei21; E = Ec; stg = stg21; cap = CAPE; }
    else             { key = eidx;      pay = nullptr; E = Pc; stg = stgm; cap = CAPP; }
    int chunk = (E + NBLK - 1) / NBLK;
    int start = blk * chunk;
    int stop = min(start + chunk, E);
    __shared__ int cnt[NPART];
    __shared__ int base[NPART];
    __shared__ int fill[NPART];
    if (t < NPART) cnt[t] = 0;
    __syncthreads();
    for (int e = start + t; e < stop; e += 256)
        atomicAdd(&cnt[key[e] / NPc], 1);
    __syncthreads();
    if (t < NPART) {
        base[t] = cnt[t] ? atomicAdd(&gcnt[z * NPART + t], cnt[t]) : 0;
        fill[t] = 0;
    }
    __syncthreads();
    for (int e = start + t; e < stop; e += 256) {
        unsigned int k = (unsigned int)key[e];
        int p = (int)(k / NPc);
        int r = atomicAdd(&fill[p], 1);
        unsigned int pk = (z == 2) ? ((k << 18) | (unsigned int)e)
                                   : ((k << 14) | (unsigned int)pay[e]);
        stg[(size_t)p * cap + base[p] + r] = pk;
    }
}

__global__ __launch_bounds__(256) void build_csr_kernel(
    const int* __restrict__ gcnt,
    const unsigned int* __restrict__ stg12, const unsigned int* __restrict__ stg21,
    const unsigned int* __restrict__ stgm,
    int* __restrict__ rp12, int* __restrict__ rp21, int* __restrict__ rpm,
    int* __restrict__ es12, int* __restrict__ es21, int* __restrict__ ps)
{
    int p = blockIdx.x, z = blockIdx.y, t = threadIdx.x;
    const unsigned int* stg; int* rowptr; int* out; int cap;
    if (z == 0)      { stg = stg12; rowptr = rp12; out = es12; cap = CAPE; }
    else if (z == 1) { stg = stg21; rowptr = rp21; out = es21; cap = CAPE; }
    else             { stg = stgm;  rowptr = rpm;  out = ps;   cap = CAPP; }
    int ksh = (z == 2) ? 18 : 14;
    unsigned int pmask = (z == 2) ? 0x3FFFFu : 0x3FFFu;
    int baseOut = 0, cntP = 0;
    #pragma unroll
    for (int j = 0; j < NPART; j++) {
        int c = gcnt[z * NPART + j];
        if (j < p) baseOut += c;
        if (j == p) cntP = c;
    }
    const unsigned int* sbase = stg + (size_t)p * cap;
    int lo = p * NPc;
    int hi = min(lo + NPc, 10000);

    __shared__ int hist[512];
    __shared__ int fill[NPc];
    hist[t] = 0; hist[t + 256] = 0;
    __syncthreads();
    for (int i = t; i < cntP; i += 256)
        atomicAdd(&hist[(int)(sbase[i] >> ksh) - lo], 1);
    __syncthreads();
    for (int off = 1; off < 512; off <<= 1) {
        int i0 = t, i1 = t + 256;
        int v0 = (i0 >= off) ? hist[i0 - off] : 0;
        int v1 = (i1 >= off) ? hist[i1 - off] : 0;
        __syncthreads();
        hist[i0] += v0; hist[i1] += v1;
        __syncthreads();
    }
    for (int i = t; i < NPc; i += 256) {
        int excl = i ? hist[i - 1] : 0;
        fill[i] = excl;
        if (lo + i < hi) rowptr[lo + i] = baseOut + excl;
    }
    if (p == NPART - 1 && t == 0) rowptr[10000] = baseOut + cntP;
    __syncthreads();
    for (int i = t; i < cntP; i += 256) {
        unsigned int pk = sbase[i];
        int r = atomicAdd(&fill[(int)(pk >> ksh) - lo], 1);
        out[baseOut + r] = (int)(pk & pmask);
    }
}

// ---------------- bf16 MFMA GEMM: 64x(64*NS) tile, 4 waves, 16x16x32, K unrolled ----------
// PACKQKV: col<128 -> Qb bf16; col in [128,384) -> interleaved fp8 KV8
template<int A_GELU, int OUT_RELU, int SKIP, int PACKQKV, int ABF, int KT, int NS>
__global__ __launch_bounds__(256) void gemm_mfma(
    const void* __restrict__ A0v, const void* __restrict__ A1v, int ldA,
    const short* __restrict__ Wt0, const short* __restrict__ Wt1,
    const float* __restrict__ b0, const float* __restrict__ b1,
    unsigned short* __restrict__ C0, unsigned short* __restrict__ C1, int ldC,
    unsigned char* __restrict__ KV8o0, unsigned char* __restrict__ KV8o1,
    int M,
    const float* __restrict__ sk0, const float* __restrict__ sk1,
    const unsigned short* __restrict__ H0, const unsigned short* __restrict__ H1, int ldH)
{
    int z = blockIdx.z;
    const void* Av = z ? A1v : A0v;
    const short* Wt = z ? Wt1 : Wt0;
    const float* bias = z ? b1 : b0;
    unsigned short* C = z ? C1 : C0;
    unsigned char* KV8o = z ? KV8o1 : KV8o0;
    const float* skipv = z ? sk1 : sk0;
    const unsigned short* Hold = z ? H1 : H0;

    __shared__ short Alds[64 * 40];
    __shared__ short Blds[64 * NS * 40];

    int tid = threadIdx.x;
    int w = tid >> 6;
    int l = tid & 63;
    int mBase = blockIdx.x * 64;
    int nBase = blockIdx.y * 64 * NS;

    int srow = tid >> 2;
    int koct = tid & 3;

    float4v acc[NS][4];
    #pragma unroll
    for (int s = 0; s < NS; s++)
        #pragma unroll
        for (int i = 0; i < 4; i++) acc[s][i] = (float4v){0.f, 0.f, 0.f, 0.f};

    int arow = mBase + srow;

    int fl = l & 15;
    int fo = (l >> 4) * 8;

    #pragma unroll
    for (int k0 = 0; k0 < KT; k0 += 32) {
        uint4 raw;
        if (ABF) {
            const unsigned short* Ab = (const unsigned short*)Av;
            raw = make_uint4(0u, 0u, 0u, 0u);
            if (arow < M) raw = *(const uint4*)(Ab + (size_t)arow * ldA + k0 + koct * 8);
            if (A_GELU) {
                unsigned int wd[4] = {raw.x, raw.y, raw.z, raw.w};
                #pragma unroll
                for (int i = 0; i < 4; i++) {
                    float lo = gelu_f(bf2f((unsigned short)(wd[i] & 0xFFFFu)));
                    float hi = gelu_f(bf2f((unsigned short)(wd[i] >> 16)));
                    wd[i] = (unsigned int)f2bf(lo) | ((unsigned int)f2bf(hi) << 16);
                }
                raw = make_uint4(wd[0], wd[1], wd[2], wd[3]);
            }
        } else {
            const float* Af = (const float*)Av;
            float av[8];
            if (arow < M) {
                const float4* p = (const float4*)(Af + (size_t)arow * ldA + k0 + koct * 8);
                float4 f0 = p[0], f1 = p[1];
                av[0]=f0.x; av[1]=f0.y; av[2]=f0.z; av[3]=f0.w;
                av[4]=f1.x; av[5]=f1.y; av[6]=f1.z; av[7]=f1.w;
            } else {
                #pragma unroll
                for (int i = 0; i < 8; i++) av[i] = 0.f;
            }
            unsigned int pk[4];
            #pragma unroll
            for (int i = 0; i < 4; i++)
                pk[i] = (unsigned int)f2bf(av[2*i]) | ((unsigned int)f2bf(av[2*i+1]) << 16);
            raw = make_uint4(pk[0], pk[1], pk[2], pk[3]);
        }
        *(uint4*)&Alds[srow * 40 + koct * 8] = raw;
        #pragma unroll
        for (int r = 0; r < NS; r++) {
            int nrow = nBase + r * 64 + srow;
            *(uint4*)&Blds[(r * 64 + srow) * 40 + koct * 8] =
                *(const uint4*)(Wt + (size_t)nrow * KT + k0 + koct * 8);
        }
        __syncthreads();

        #pragma unroll
        for (int s = 0; s < NS; s++) {
            short8 bfr = *(const short8*)&Blds[(s * 64 + w * 16 + fl) * 40 + fo];
            #pragma unroll
            for (int msub = 0; msub < 4; msub++) {
                short8 afr = *(const short8*)&Alds[(msub * 16 + fl) * 40 + fo];
                acc[s][msub] = __builtin_amdgcn_mfma_f32_16x16x32_bf16(afr, bfr, acc[s][msub], 0, 0, 0);
            }
        }
        __syncthreads();
    }

    float sig = 0.f;
    if (SKIP) sig = 1.f / (1.f + __expf(-skipv[0]));
    int rbase = mBase + ((l >> 4) * 4);
    #pragma unroll
    for (int s = 0; s < NS; s++) {
        int col = nBase + s * 64 + w * 16 + fl;
        float bcol = bias[col];
        #pragma unroll
        for (int msub = 0; msub < 4; msub++) {
            #pragma unroll
            for (int r = 0; r < 4; r++) {
                int row = rbase + msub * 16 + r;
                if (row >= M) continue;
                float v = acc[s][msub][r] + bcol;
                if (OUT_RELU) v = fmaxf(v, 0.f);
                if (SKIP) v = sig * v + (1.f - sig) * bf2f(Hold[(size_t)row * ldH + col]);
                if (PACKQKV) {
                    if (col < 128) {
                        C[(size_t)row * ldC + col] = f2bf(v);
                    } else if (col < 256) {
                        int c = col - 128;
                        KV8o[(size_t)row * 256 + (c >> 3) * 16 + (c & 7)] = f2fp8(v);
                    } else {
                        int c = col - 256;
                        KV8o[(size_t)row * 256 + (c >> 3) * 16 + 8 + (c & 7)] = f2fp8(v);
                    }
                } else {
                    C[(size_t)row * ldC + col] = f2bf(v);
                }
            }
        }
    }
}

// ---------------- attend: both directions; 4 nodes/block, 32 lanes/node (2 edge-groups) ----
// lane layout: nid=tid>>5, l32=tid&31, g=l32>>4 (edge half), ln=l32&15 (cols 8*ln..+8)
// each group partial-softmaxes half the edge list (no max-shift -> sums merge exactly)
__global__ __launch_bounds__(128) void attend_kernel(
    const unsigned short* __restrict__ Qb1, const unsigned char* __restrict__ KV81,
    const unsigned short* __restrict__ Qb2, const unsigned char* __restrict__ KV82,
    const int* __restrict__ rp12, const int* __restrict__ es12,
    const int* __restrict__ rp21, const int* __restrict__ es21,
    unsigned short* __restrict__ agg1, unsigned short* __restrict__ agg2)
{
    int b = blockIdx.x;
    int nid = threadIdx.x >> 5;
    int l32 = threadIdx.x & 31;
    int g = l32 >> 4;
    int ln = l32 & 15;
    const unsigned short* Qb; const unsigned char* KV; const int* rp; const int* es;
    unsigned short* outb; int n;
    if (b < 2500) { n = b * 4 + nid;          Qb = Qb2; KV = KV81; rp = rp12; es = es12; outb = agg2; }
    else          { n = (b - 2500) * 4 + nid; Qb = Qb1; KV = KV82; rp = rp21; es = es21; outb = agg1; }

    float q[8];
    {
        const ushort4* qp = (const ushort4*)(Qb + (size_t)n * 128 + 8 * ln);
        ushort4 qa = qp[0], qc = qp[1];
        q[0]=bf2f(qa.x); q[1]=bf2f(qa.y); q[2]=bf2f(qa.z); q[3]=bf2f(qa.w);
        q[4]=bf2f(qc.x); q[5]=bf2f(qc.y); q[6]=bf2f(qc.z); q[7]=bf2f(qc.w);
    }
    int beg = rp[n], end = rp[n + 1];
    int cnt = end - beg;
    int half = (cnt + 1) >> 1;
    int gbeg = beg + g * half;
    int gend = g ? end : (beg + half);

    float s = 0.f;
    float acc[8];
    #pragma unroll
    for (int c = 0; c < 8; c++) acc[c] = 0.f;

    auto dec8 = [&](unsigned int w0, unsigned int w1, float* d) {
        floatx2 a0 = __builtin_amdgcn_cvt_pk_f32_fp8(w0, false);
        floatx2 a1 = __builtin_amdgcn_cvt_pk_f32_fp8(w0, true);
        floatx2 a2 = __builtin_amdgcn_cvt_pk_f32_fp8(w1, false);
        floatx2 a3 = __builtin_amdgcn_cvt_pk_f32_fp8(w1, true);
        d[0]=a0[0]; d[1]=a0[1]; d[2]=a1[0]; d[3]=a1[1];
        d[4]=a2[0]; d[5]=a2[1]; d[6]=a3[0]; d[7]=a3[1];
    };
    auto proc1 = [&](uint4 kv) {
        float kd[8], vd[8];
        dec8(kv.x, kv.y, kd);
        float p = q[0]*kd[0] + q[1]*kd[1] + q[2]*kd[2] + q[3]*kd[3]
                + q[4]*kd[4] + q[5]*kd[5] + q[6]*kd[6] + q[7]*kd[7];
        p += __shfl_xor(p, 1, 2);
        float x = __expf(p);
        s += x;
        dec8(kv.z, kv.w, vd);
        #pragma unroll
        for (int c = 0; c < 8; c++) acc[c] += x * vd[c];
    };
    auto ld = [&](int e) { return *(const uint4*)(KV + (size_t)e * 256 + 16 * ln); };

    int i = gbeg;
    int pre = min(gend, (gbeg + 3) & ~3);
    for (; i < pre; i++) proc1(ld(es[i]));
    for (; i + 8 <= gend; i += 8) {
        int4 ea = *(const int4*)&es[i];
        int4 eb = *(const int4*)&es[i + 4];
        uint4 w0 = ld(ea.x), w1 = ld(ea.y), w2 = ld(ea.z), w3 = ld(ea.w);
        uint4 w4 = ld(eb.x), w5 = ld(eb.y), w6 = ld(eb.z), w7 = ld(eb.w);
        proc1(w0); proc1(w1); proc1(w2); proc1(w3);
        proc1(w4); proc1(w5); proc1(w6); proc1(w7);
    }
    for (; i + 4 <= gend; i += 4) {
        int4 ea = *(const int4*)&es[i];
        uint4 w0 = ld(ea.x), w1 = ld(ea.y), w2 = ld(ea.z), w3 = ld(ea.w);
        proc1(w0); proc1(w1); proc1(w2); proc1(w3);
    }
    for (; i < gend; i++) proc1(ld(es[i]));

    // merge the two edge-groups (plain sums: exact)
    s += __shfl_xor(s, 16, 32);
    #pragma unroll
    for (int c = 0; c < 8; c++) acc[c] += __shfl_xor(acc[c], 16, 32);

    if (g == 0) {
        float inv = 1.f / (s + 1e-16f);
        unsigned int w0 = (unsigned int)f2bf(acc[0]*inv) | ((unsigned int)f2bf(acc[1]*inv) << 16);
        unsigned int w1 = (unsigned int)f2bf(acc[2]*inv) | ((unsigned int)f2bf(acc[3]*inv) << 16);
        unsigned int w2 = (unsigned int)f2bf(acc[4]*inv) | ((unsigned int)f2bf(acc[5]*inv) << 16);
        unsigned int w3 = (unsigned int)f2bf(acc[6]*inv) | ((unsigned int)f2bf(acc[7]*inv) << 16);
        *(uint4*)(outb + (size_t)n * 128 + 8 * ln) = make_uint4(w0, w1, w2, w3);
    }
}

// ---------------- pred: 4 m/block, 4 pair-groups of 16 lanes per wave ----------------
__global__ __launch_bounds__(256) void pred_kernel(
    const unsigned short* __restrict__ Emb, const unsigned short* __restrict__ Edb,
    const int* __restrict__ eidx,
    const int* __restrict__ rpm, const int* __restrict__ porder,
    float* __restrict__ out)
{
    int m = blockIdx.x * 4 + (threadIdx.x >> 6);
    int l = threadIdx.x & 63;
    int g = l >> 4;
    int ln = l & 15;
    int beg = rpm[m], end = rpm[m + 1];
    if (beg == end) return;
    float a[16];
    {
        const uint4* ap = (const uint4*)(Emb + (size_t)m * 256 + 16 * ln);
        uint4 u0 = ap[0], u1 = ap[1];
        unsigned int wv[8] = {u0.x, u0.y, u0.z, u0.w, u1.x, u1.y, u1.z, u1.w};
        #pragma unroll
        for (int i = 0; i < 8; i++) {
            a[2*i]   = bf2f((unsigned short)(wv[i] & 0xFFFFu));
            a[2*i+1] = bf2f((unsigned short)(wv[i] >> 16));
        }
    }
    for (int i = beg + g; i < end; i += 4) {
        int p = porder[i];
        int d = eidx[Pc + p];
        const uint4* bp = (const uint4*)(Edb + (size_t)d * 256 + 16 * ln);
        uint4 u0 = bp[0], u1 = bp[1];
        unsigned int wv[8] = {u0.x, u0.y, u0.z, u0.w, u1.x, u1.y, u1.z, u1.w};
        float s = 0.f;
        #pragma unroll
        for (int j = 0; j < 8; j++)
            s += a[2*j] * bf2f((unsigned short)(wv[j] & 0xFFFFu))
               + a[2*j+1] * bf2f((unsigned short)(wv[j] >> 16));
        s += __shfl_xor(s, 1, 16);
        s += __shfl_xor(s, 2, 16);
        s += __shfl_xor(s, 4, 16);
        s += __shfl_xor(s, 8, 16);
        if (ln == 0) out[p] = s;
    }
}

extern "C" void kernel_launch(void* const* d_in, const int* in_sizes, int n_in,
                              void* d_out, int out_size, void* d_ws, size_t ws_size,
                              hipStream_t stream)
{
    const float* x1   = (const float*)d_in[0];
    const float* x2   = (const float*)d_in[1];
    const int*   ei12 = (const int*)d_in[2];
    const int*   ei21 = (const int*)d_in[3];
    const int*   eidx = (const int*)d_in[4];
    const float* Win1 = (const float*)d_in[5];
    const float* bin1 = (const float*)d_in[6];
    const float* Win2 = (const float*)d_in[7];
    const float* bin2 = (const float*)d_in[8];
    const float* Wk   = (const float*)d_in[9];
    const float* bk   = (const float*)d_in[10];
    const float* Wq   = (const float*)d_in[11];
    const float* bq   = (const float*)d_in[12];
    const float* Wv   = (const float*)d_in[13];
    const float* bv   = (const float*)d_in[14];
    const float* Wa   = (const float*)d_in[15];
    const float* ba   = (const float*)d_in[16];
    const float* skip = (const float*)d_in[17];
    const float* arel = (const float*)d_in[18];
    const float* mrel = (const float*)d_in[19];
    const float* prior= (const float*)d_in[20];

    char* ws = (char*)d_ws;
    size_t off = 0;
    auto allocB = [&](size_t bytes) { void* p = ws + off; off += (bytes + 15) & ~15ull; return p; };
    auto allocF = [&](size_t n) { return (float*)allocB(n * 4); };
    auto allocI = [&](size_t n) { return (int*)allocB(n * 4); };
    auto allocS = [&](size_t n) { return (short*)allocB(n * 2); };
    auto allocU = [&](size_t n) { return (unsigned short*)allocB(n * 2); };

    unsigned short* h1b  = allocU((size_t)N1c * 128);
    unsigned short* h2b  = allocU((size_t)N2c * 128);
    unsigned short* Qb1  = allocU((size_t)N1c * 128);
    unsigned short* Qb2  = allocU((size_t)N2c * 128);
    unsigned char*  KV81 = (unsigned char*)allocB((size_t)N1c * 256);
    unsigned char*  KV82 = (unsigned char*)allocB((size_t)N2c * 256);
    unsigned short* agg1 = allocU((size_t)N1c * 128);
    unsigned short* agg2 = allocU((size_t)N2c * 128);
    unsigned short* Emb  = allocU((size_t)N1c * 256);
    unsigned short* Edb  = allocU((size_t)N2c * 256);
    float* bqkv  = allocF(4 * 384);
    short* Wqkvt = allocS(4 * 384 * 128);
    short* Wint1 = allocS(128 * 256);
    short* Wint2 = allocS(128 * 256);
    short* Wat   = allocS(4 * 128 * 128);
    int* rp12  = allocI(N2c + 1);
    int* rp21  = allocI(N1c + 1);
    int* rpm   = allocI(N1c + 1);
    int* es12  = allocI(Ec);
    int* es21  = allocI(Ec);
    int* ps    = allocI(Pc);
    int* gcnt  = allocI(3 * NPART);
    unsigned int* stg12 = (unsigned int*)allocB((size_t)NPART * CAPE * 4);
    unsigned int* stg21 = (unsigned int*)allocB((size_t)NPART * CAPE * 4);
    unsigned int* stgm  = (unsigned int*)allocB((size_t)NPART * CAPP * 4);

    prep_kernel<<<1280, 256, 0, stream>>>(
        Wq, bq, Wk, bk, Wv, bv, arel, mrel, prior,
        Win1, Win2, Wa, Wqkvt, bqkv, Wint1, Wint2, Wat, gcnt);

    scatter_bins_kernel<<<dim3(NBLK, 3), 256, 0, stream>>>(
        ei12, ei21, eidx, gcnt, stg12, stg21, stgm);
    build_csr_kernel<<<dim3(NPART, 3), 256, 0, stream>>>(
        gcnt, stg12, stg21, stgm, rp12, rp21, rpm, es12, es21, ps);

    const int MB = (N1c + 63) / 64;   // 157
    // input projections (relu): fp32 A, K=256 -> bf16 h
    gemm_mfma<0, 1, 0, 0, 0, 256, 1><<<dim3(MB, 2, 2), 256, 0, stream>>>(
        x1, x2, F_INc, Wint1, Wint2, bin1, bin2, h1b, h2b, 128,
        nullptr, nullptr,
        N1c, nullptr, nullptr, nullptr, nullptr, 0);

    for (int l = 0; l < Lc; l++) {
        const unsigned short* A1 = (l == 0) ? h1b : Emb;  int ld1 = (l == 0) ? 128 : 256;
        const unsigned short* A2 = (l == 0) ? h2b : Edb;
        int lt0 = l * 2 + 0, lt1 = l * 2 + 1;
        // fused QKV projections: Q bf16, interleaved fp8 KV; 2 n-strips/block
        gemm_mfma<0, 0, 0, 1, 1, 128, 2><<<dim3(MB, 3, 2), 256, 0, stream>>>(
            A1, A2, ld1,
            Wqkvt + (size_t)lt0 * 49152, Wqkvt + (size_t)lt1 * 49152,
            bqkv + lt0 * 384, bqkv + lt1 * 384,
            Qb1, Qb2, 128,
            KV81, KV82,
            N1c, nullptr, nullptr, nullptr, nullptr, 0);
        // both attends, one dispatch (5000 blocks; 4 nodes x 32 lanes each)
        attend_kernel<<<(N1c + N2c) / 4, 128, 0, stream>>>(
            Qb1, KV81, Qb2, KV82, rp12, es12, rp21, es21, agg1, agg2);
        // output GEMMs (gelu on bf16 A, skip blend vs bf16 Hold) into concat buffers
        gemm_mfma<1, 0, 1, 0, 1, 128, 1><<<dim3(MB, 2, 2), 256, 0, stream>>>(
            agg1, agg2, 128,
            Wat + (size_t)lt0 * 16384, Wat + (size_t)lt1 * 16384,
            ba + lt0 * 128, ba + lt1 * 128,
            Emb + l * 128, Edb + l * 128, 256,
            nullptr, nullptr,
            N1c,
            skip + lt0, skip + lt1,
            A1, A2, ld1);
    }

    pred_kernel<<<N1c / 4, 256, 0, stream>>>(Emb, Edb, eidx, rpm, ps, (float*)d_out);
}

// Round 16
// 304.488 us; speedup vs baseline: 1.0237x; 1.0237x over previous
//
#include <hip/hip_runtime.h>
#include <math.h>

#define N1c 10000
#define N2c 10000
#define F_INc 256
#define Ec 480000
#define Pc 200000
#define Lc 2
#define NPART 32
#define NPc 313    // ceil(10000/32)
#define NBLK 256   // chunks per edge structure
#define CAPE 17408 // per-partition staging capacity, edges
#define CAPP 7936  // per-partition staging capacity, pairs

using short8 = __attribute__((ext_vector_type(8))) short;
using float4v = __attribute__((ext_vector_type(4))) float;
using floatx2 = __attribute__((ext_vector_type(2))) float;

__device__ __forceinline__ float gelu_f(float x) {
    const float k0 = 0.7978845608028654f;
    const float k1 = 0.044715f;
    float x3 = x * x * x;
    float t = tanhf(k0 * (x + k1 * x3));
    return 0.5f * x * (1.0f + t);
}

__device__ __forceinline__ float bf2f(unsigned short x) {
    union { unsigned int u; float f; } c;
    c.u = ((unsigned int)x) << 16;
    return c.f;
}
__device__ __forceinline__ unsigned short f2bf(float f) {
    union { float f; unsigned int u; } c;
    c.f = f;
    unsigned int u = c.u;
    unsigned int r = (u + 0x7FFFu + ((u >> 16) & 1u)) >> 16;
    return (unsigned short)r;
}
__device__ __forceinline__ unsigned char f2fp8(float v) {
    unsigned int p = __builtin_amdgcn_cvt_pk_fp8_f32(v, v, 0u, false);
    return (unsigned char)(p & 0xFF);
}

// ---------------- merged weight prep (also zeroes gcnt) ----------------
__global__ __launch_bounds__(256) void prep_kernel(
    const float* __restrict__ Wq, const float* __restrict__ bq,
    const float* __restrict__ Wk, const float* __restrict__ bk,
    const float* __restrict__ Wv, const float* __restrict__ bv,
    const float* __restrict__ arel, const float* __restrict__ mrel,
    const float* __restrict__ prior,
    const float* __restrict__ Win1, const float* __restrict__ Win2,
    const float* __restrict__ Wa,
    short* __restrict__ Wqkvt, float* __restrict__ bqkv,
    short* __restrict__ Wint1, short* __restrict__ Wint2, short* __restrict__ Wat,
    int* __restrict__ gcnt)
{
    if (blockIdx.x == 0 && threadIdx.x < 3 * NPART) gcnt[threadIdx.x] = 0;
    int id = blockIdx.x * 256 + threadIdx.x;
    if (id < 196608) {
        int lt = id / 49152;
        int r = id - lt * 49152;
        int col = r >> 7, c = r & 127;
        short* Wout = Wqkvt + (size_t)lt * 384 * 128;
        float* bout = bqkv + lt * 384;
        if (col < 128) {
            Wout[col * 128 + c] = (short)f2bf(Wq[lt * 16384 + c * 128 + col]);
            if (c == 0) bout[col] = bq[lt * 128 + col];
            return;
        }
        int which = (col < 256) ? 0 : 1;
        int he = col - (which ? 256 : 128);
        int h = he >> 4, e = he & 15;
        const float* W = (which == 0 ? Wk : Wv) + lt * 16384;
        const float* b = (which == 0 ? bk : bv) + lt * 128;
        const float* R = (which == 0 ? arel : mrel) + lt * 2048;
        float sc = (which == 0) ? prior[lt * 8 + h] * 0.25f : 1.0f;
        float acc = 0.f;
        #pragma unroll
        for (int d = 0; d < 16; d++)
            acc += W[c * 128 + h * 16 + d] * R[(h * 16 + d) * 16 + e];
        Wout[col * 128 + c] = (short)f2bf(acc * sc);
        if (c == 0) {
            float bacc = 0.f;
            #pragma unroll
            for (int d = 0; d < 16; d++)
                bacc += b[h * 16 + d] * R[(h * 16 + d) * 16 + e];
            bout[col] = bacc * sc;
        }
    } else {
        int wid = id - 196608;
        if (wid < 65536) {
            int y = wid >> 15;
            int id2 = wid & 32767;
            int n = id2 >> 8, k = id2 & 255;
            const float* W = y ? Win2 : Win1;
            short* O = y ? Wint2 : Wint1;
            O[n * 256 + k] = (short)f2bf(W[k * 128 + n]);
        } else {
            int wid2 = wid - 65536;
            int lt = wid2 >> 14;
            int id2 = wid2 & 16383;
            int n = id2 >> 7, k = id2 & 127;
            Wat[lt * 16384 + n * 128 + k] = (short)f2bf(Wa[lt * 16384 + k * 128 + n]);
        }
    }
}

// ---------------- CSR: single-pass binning + build ----------------
__global__ __launch_bounds__(256) void scatter_bins_kernel(
    const int* __restrict__ ei12, const int* __restrict__ ei21, const int* __restrict__ eidx,
    int* __restrict__ gcnt,
    unsigned int* __restrict__ stg12, unsigned int* __restrict__ stg21,
    unsigned int* __restrict__ stgm)
{
    int blk = blockIdx.x, z = blockIdx.y, t = threadIdx.x;
    const int* key; const int* pay; int E; unsigned int* stg; int cap;
    if (z == 0)      { key = ei12 + Ec; pay = ei12; E = Ec; stg = stg12; cap = CAPE; }
    else if (z == 1) { key = ei21 + Ec; pay = ei21; E = Ec; stg = stg21; cap = CAPE; }
    else             { key = eidx;      pay = nullptr; E = Pc; stg = stgm; cap = CAPP; }
    int chunk = (E + NBLK - 1) / NBLK;
    int start = blk * chunk;
    int stop = min(start + chunk, E);
    __shared__ int cnt[NPART];
    __shared__ int base[NPART];
    __shared__ int fill[NPART];
    if (t < NPART) cnt[t] = 0;
    __syncthreads();
    for (int e = start + t; e < stop; e += 256)
        atomicAdd(&cnt[key[e] / NPc], 1);
    __syncthreads();
    if (t < NPART) {
        base[t] = cnt[t] ? atomicAdd(&gcnt[z * NPART + t], cnt[t]) : 0;
        fill[t] = 0;
    }
    __syncthreads();
    for (int e = start + t; e < stop; e += 256) {
        unsigned int k = (unsigned int)key[e];
        int p = (int)(k / NPc);
        int r = atomicAdd(&fill[p], 1);
        unsigned int pk = (z == 2) ? ((k << 18) | (unsigned int)e)
                                   : ((k << 14) | (unsigned int)pay[e]);
        stg[(size_t)p * cap + base[p] + r] = pk;
    }
}

__global__ __launch_bounds__(256) void build_csr_kernel(
    const int* __restrict__ gcnt,
    const unsigned int* __restrict__ stg12, const unsigned int* __restrict__ stg21,
    const unsigned int* __restrict__ stgm,
    int* __restrict__ rp12, int* __restrict__ rp21, int* __restrict__ rpm,
    int* __restrict__ es12, int* __restrict__ es21, int* __restrict__ ps)
{
    int p = blockIdx.x, z = blockIdx.y, t = threadIdx.x;
    const unsigned int* stg; int* rowptr; int* out; int cap;
    if (z == 0)      { stg = stg12; rowptr = rp12; out = es12; cap = CAPE; }
    else if (z == 1) { stg = stg21; rowptr = rp21; out = es21; cap = CAPE; }
    else             { stg = stgm;  rowptr = rpm;  out = ps;   cap = CAPP; }
    int ksh = (z == 2) ? 18 : 14;
    unsigned int pmask = (z == 2) ? 0x3FFFFu : 0x3FFFu;
    int baseOut = 0, cntP = 0;
    #pragma unroll
    for (int j = 0; j < NPART; j++) {
        int c = gcnt[z * NPART + j];
        if (j < p) baseOut += c;
        if (j == p) cntP = c;
    }
    const unsigned int* sbase = stg + (size_t)p * cap;
    int lo = p * NPc;
    int hi = min(lo + NPc, 10000);

    __shared__ int hist[512];
    __shared__ int fill[NPc];
    hist[t] = 0; hist[t + 256] = 0;
    __syncthreads();
    for (int i = t; i < cntP; i += 256)
        atomicAdd(&hist[(int)(sbase[i] >> ksh) - lo], 1);
    __syncthreads();
    for (int off = 1; off < 512; off <<= 1) {
        int i0 = t, i1 = t + 256;
        int v0 = (i0 >= off) ? hist[i0 - off] : 0;
        int v1 = (i1 >= off) ? hist[i1 - off] : 0;
        __syncthreads();
        hist[i0] += v0; hist[i1] += v1;
        __syncthreads();
    }
    for (int i = t; i < NPc; i += 256) {
        int excl = i ? hist[i - 1] : 0;
        fill[i] = excl;
        if (lo + i < hi) rowptr[lo + i] = baseOut + excl;
    }
    if (p == NPART - 1 && t == 0) rowptr[10000] = baseOut + cntP;
    __syncthreads();
    for (int i = t; i < cntP; i += 256) {
        unsigned int pk = sbase[i];
        int r = atomicAdd(&fill[(int)(pk >> ksh) - lo], 1);
        out[baseOut + r] = (int)(pk & pmask);
    }
}

// ---------------- bf16 MFMA GEMM: 64x64 tile, 4 waves, 16x16x32, K unrolled ----------------
// PACKQKV: col<128 -> Qb bf16; col in [128,384) -> interleaved fp8 KV8
template<int A_GELU, int OUT_RELU, int SKIP, int PACKQKV, int ABF, int KT>
__global__ __launch_bounds__(256) void gemm_mfma(
    const void* __restrict__ A0v, const void* __restrict__ A1v, int ldA,
    const short* __restrict__ Wt0, const short* __restrict__ Wt1,
    const float* __restrict__ b0, const float* __restrict__ b1,
    unsigned short* __restrict__ C0, unsigned short* __restrict__ C1, int ldC,
    unsigned char* __restrict__ KV8o0, unsigned char* __restrict__ KV8o1,
    int M,
    const float* __restrict__ sk0, const float* __restrict__ sk1,
    const unsigned short* __restrict__ H0, const unsigned short* __restrict__ H1, int ldH)
{
    int z = blockIdx.z;
    const void* Av = z ? A1v : A0v;
    const short* Wt = z ? Wt1 : Wt0;
    const float* bias = z ? b1 : b0;
    unsigned short* C = z ? C1 : C0;
    unsigned char* KV8o = z ? KV8o1 : KV8o0;
    const float* skipv = z ? sk1 : sk0;
    const unsigned short* Hold = z ? H1 : H0;

    __shared__ short Alds[64 * 40];
    __shared__ short Blds[64 * 40];

    int tid = threadIdx.x;
    int w = tid >> 6;
    int l = tid & 63;
    int mBase = blockIdx.x * 64;
    int nBase = blockIdx.y * 64;

    int srow = tid >> 2;
    int koct = tid & 3;

    float4v acc[4];
    #pragma unroll
    for (int i = 0; i < 4; i++) acc[i] = (float4v){0.f, 0.f, 0.f, 0.f};

    int arow = mBase + srow;
    const short* Wptr = Wt + (size_t)(nBase + srow) * KT + koct * 8;

    int fl = l & 15;
    int fo = (l >> 4) * 8;

    #pragma unroll
    for (int k0 = 0; k0 < KT; k0 += 32) {
        uint4 raw;
        if (ABF) {
            const unsigned short* Ab = (const unsigned short*)Av;
            raw = make_uint4(0u, 0u, 0u, 0u);
            if (arow < M) raw = *(const uint4*)(Ab + (size_t)arow * ldA + k0 + koct * 8);
            if (A_GELU) {
                unsigned int wd[4] = {raw.x, raw.y, raw.z, raw.w};
                #pragma unroll
                for (int i = 0; i < 4; i++) {
                    float lo = gelu_f(bf2f((unsigned short)(wd[i] & 0xFFFFu)));
                    float hi = gelu_f(bf2f((unsigned short)(wd[i] >> 16)));
                    wd[i] = (unsigned int)f2bf(lo) | ((unsigned int)f2bf(hi) << 16);
                }
                raw = make_uint4(wd[0], wd[1], wd[2], wd[3]);
            }
        } else {
            const float* Af = (const float*)Av;
            float av[8];
            if (arow < M) {
                const float4* p = (const float4*)(Af + (size_t)arow * ldA + k0 + koct * 8);
                float4 f0 = p[0], f1 = p[1];
                av[0]=f0.x; av[1]=f0.y; av[2]=f0.z; av[3]=f0.w;
                av[4]=f1.x; av[5]=f1.y; av[6]=f1.z; av[7]=f1.w;
            } else {
                #pragma unroll
                for (int i = 0; i < 8; i++) av[i] = 0.f;
            }
            unsigned int pk[4];
            #pragma unroll
            for (int i = 0; i < 4; i++)
                pk[i] = (unsigned int)f2bf(av[2*i]) | ((unsigned int)f2bf(av[2*i+1]) << 16);
            raw = make_uint4(pk[0], pk[1], pk[2], pk[3]);
        }
        *(uint4*)&Alds[srow * 40 + koct * 8] = raw;
        *(uint4*)&Blds[srow * 40 + koct * 8] = *(const uint4*)(Wptr + k0);
        __syncthreads();

        short8 bfr = *(const short8*)&Blds[(w * 16 + fl) * 40 + fo];
        #pragma unroll
        for (int msub = 0; msub < 4; msub++) {
            short8 afr = *(const short8*)&Alds[(msub * 16 + fl) * 40 + fo];
            acc[msub] = __builtin_amdgcn_mfma_f32_16x16x32_bf16(afr, bfr, acc[msub], 0, 0, 0);
        }
        __syncthreads();
    }

    float sig = 0.f;
    if (SKIP) sig = 1.f / (1.f + __expf(-skipv[0]));
    int col = nBase + w * 16 + fl;
    float bcol = bias[col];
    int rbase = mBase + ((l >> 4) * 4);
    #pragma unroll
    for (int msub = 0; msub < 4; msub++) {
        #pragma unroll
        for (int r = 0; r < 4; r++) {
            int row = rbase + msub * 16 + r;
            if (row >= M) continue;
            float v = acc[msub][r] + bcol;
            if (OUT_RELU) v = fmaxf(v, 0.f);
            if (SKIP) v = sig * v + (1.f - sig) * bf2f(Hold[(size_t)row * ldH + col]);
            if (PACKQKV) {
                if (col < 128) {
                    C[(size_t)row * ldC + col] = f2bf(v);
                } else if (col < 256) {
                    int c = col - 128;
                    KV8o[(size_t)row * 256 + (c >> 3) * 16 + (c & 7)] = f2fp8(v);
                } else {
                    int c = col - 256;
                    KV8o[(size_t)row * 256 + (c >> 3) * 16 + 8 + (c & 7)] = f2fp8(v);
                }
            } else {
                C[(size_t)row * ldC + col] = f2bf(v);
            }
        }
    }
}

// ---------------- attend: both directions, one dispatch; 1 uint4 load/edge/lane ----------
__global__ __launch_bounds__(128) void attend_kernel(
    const unsigned short* __restrict__ Qb1, const unsigned char* __restrict__ KV81,
    const unsigned short* __restrict__ Qb2, const unsigned char* __restrict__ KV82,
    const int* __restrict__ rp12, const int* __restrict__ es12,
    const int* __restrict__ rp21, const int* __restrict__ es21,
    unsigned short* __restrict__ agg1, unsigned short* __restrict__ agg2)
{
    int b = blockIdx.x;
    const unsigned short* Qb; const unsigned char* KV; const int* rp; const int* es;
    unsigned short* outb; int n;
    if (b < 1250) { n = b * 8 + (threadIdx.x >> 4);          Qb = Qb2; KV = KV81; rp = rp12; es = es12; outb = agg2; }
    else          { n = (b - 1250) * 8 + (threadIdx.x >> 4); Qb = Qb1; KV = KV82; rp = rp21; es = es21; outb = agg1; }
    int ln = threadIdx.x & 15;

    float q[8];
    {
        const ushort4* qp = (const ushort4*)(Qb + (size_t)n * 128 + 8 * ln);
        ushort4 qa = qp[0], qc = qp[1];
        q[0]=bf2f(qa.x); q[1]=bf2f(qa.y); q[2]=bf2f(qa.z); q[3]=bf2f(qa.w);
        q[4]=bf2f(qc.x); q[5]=bf2f(qc.y); q[6]=bf2f(qc.z); q[7]=bf2f(qc.w);
    }
    int beg = rp[n], end = rp[n + 1];
    float s = 0.f;
    float acc[8];
    #pragma unroll
    for (int c = 0; c < 8; c++) acc[c] = 0.f;

    auto dec8 = [&](unsigned int w0, unsigned int w1, float* d) {
        floatx2 a0 = __builtin_amdgcn_cvt_pk_f32_fp8(w0, false);
        floatx2 a1 = __builtin_amdgcn_cvt_pk_f32_fp8(w0, true);
        floatx2 a2 = __builtin_amdgcn_cvt_pk_f32_fp8(w1, false);
        floatx2 a3 = __builtin_amdgcn_cvt_pk_f32_fp8(w1, true);
        d[0]=a0[0]; d[1]=a0[1]; d[2]=a1[0]; d[3]=a1[1];
        d[4]=a2[0]; d[5]=a2[1]; d[6]=a3[0]; d[7]=a3[1];
    };
    auto proc1 = [&](uint4 kv) {
        float kd[8], vd[8];
        dec8(kv.x, kv.y, kd);
        float p = q[0]*kd[0] + q[1]*kd[1] + q[2]*kd[2] + q[3]*kd[3]
                + q[4]*kd[4] + q[5]*kd[5] + q[6]*kd[6] + q[7]*kd[7];
        p += __shfl_xor(p, 1, 2);
        float x = __expf(p);
        s += x;
        dec8(kv.z, kv.w, vd);
        #pragma unroll
        for (int c = 0; c < 8; c++) acc[c] += x * vd[c];
    };
    auto ld = [&](int e) { return *(const uint4*)(KV + (size_t)e * 256 + 16 * ln); };

    int i = beg;
    int pre = min(end, (beg + 3) & ~3);
    for (; i < pre; i++) proc1(ld(es[i]));
    for (; i + 8 <= end; i += 8) {
        int4 ea = *(const int4*)&es[i];
        int4 eb = *(const int4*)&es[i + 4];
        uint4 w0 = ld(ea.x), w1 = ld(ea.y), w2 = ld(ea.z), w3 = ld(ea.w);
        uint4 w4 = ld(eb.x), w5 = ld(eb.y), w6 = ld(eb.z), w7 = ld(eb.w);
        proc1(w0); proc1(w1); proc1(w2); proc1(w3);
        proc1(w4); proc1(w5); proc1(w6); proc1(w7);
    }
    for (; i + 4 <= end; i += 4) {
        int4 ea = *(const int4*)&es[i];
        uint4 w0 = ld(ea.x), w1 = ld(ea.y), w2 = ld(ea.z), w3 = ld(ea.w);
        proc1(w0); proc1(w1); proc1(w2); proc1(w3);
    }
    for (; i < end; i++) proc1(ld(es[i]));

    float inv = 1.f / (s + 1e-16f);
    unsigned int w0 = (unsigned int)f2bf(acc[0]*inv) | ((unsigned int)f2bf(acc[1]*inv) << 16);
    unsigned int w1 = (unsigned int)f2bf(acc[2]*inv) | ((unsigned int)f2bf(acc[3]*inv) << 16);
    unsigned int w2 = (unsigned int)f2bf(acc[4]*inv) | ((unsigned int)f2bf(acc[5]*inv) << 16);
    unsigned int w3 = (unsigned int)f2bf(acc[6]*inv) | ((unsigned int)f2bf(acc[7]*inv) << 16);
    *(uint4*)(outb + (size_t)n * 128 + 8 * ln) = make_uint4(w0, w1, w2, w3);
}

// ---------------- pred: 4 m/block, 4 pair-groups of 16 lanes per wave ----------------
__global__ __launch_bounds__(256) void pred_kernel(
    const unsigned short* __restrict__ Emb, const unsigned short* __restrict__ Edb,
    const int* __restrict__ eidx,
    const int* __restrict__ rpm, const int* __restrict__ porder,
    float* __restrict__ out)
{
    int m = blockIdx.x * 4 + (threadIdx.x >> 6);
    int l = threadIdx.x & 63;
    int g = l >> 4;
    int ln = l & 15;
    int beg = rpm[m], end = rpm[m + 1];
    if (beg == end) return;
    float a[16];
    {
        const uint4* ap = (const uint4*)(Emb + (size_t)m * 256 + 16 * ln);
        uint4 u0 = ap[0], u1 = ap[1];
        unsigned int wv[8] = {u0.x, u0.y, u0.z, u0.w, u1.x, u1.y, u1.z, u1.w};
        #pragma unroll
        for (int i = 0; i < 8; i++) {
            a[2*i]   = bf2f((unsigned short)(wv[i] & 0xFFFFu));
            a[2*i+1] = bf2f((unsigned short)(wv[i] >> 16));
        }
    }
    for (int i = beg + g; i < end; i += 4) {
        int p = porder[i];
        int d = eidx[Pc + p];
        const uint4* bp = (const uint4*)(Edb + (size_t)d * 256 + 16 * ln);
        uint4 u0 = bp[0], u1 = bp[1];
        unsigned int wv[8] = {u0.x, u0.y, u0.z, u0.w, u1.x, u1.y, u1.z, u1.w};
        float s = 0.f;
        #pragma unroll
        for (int j = 0; j < 8; j++)
            s += a[2*j] * bf2f((unsigned short)(wv[j] & 0xFFFFu))
               + a[2*j+1] * bf2f((unsigned short)(wv[j] >> 16));
        s += __shfl_xor(s, 1, 16);
        s += __shfl_xor(s, 2, 16);
        s += __shfl_xor(s, 4, 16);
        s += __shfl_xor(s, 8, 16);
        if (ln == 0) out[p] = s;
    }
}

extern "C" void kernel_launch(void* const* d_in, const int* in_sizes, int n_in,
                              void* d_out, int out_size, void* d_ws, size_t ws_size,
                              hipStream_t stream)
{
    const float* x1   = (const float*)d_in[0];
    const float* x2   = (const float*)d_in[1];
    const int*   ei12 = (const int*)d_in[2];
    const int*   ei21 = (const int*)d_in[3];
    const int*   eidx = (const int*)d_in[4];
    const float* Win1 = (const float*)d_in[5];
    const float* bin1 = (const float*)d_in[6];
    const float* Win2 = (const float*)d_in[7];
    const float* bin2 = (const float*)d_in[8];
    const float* Wk   = (const float*)d_in[9];
    const float* bk   = (const float*)d_in[10];
    const float* Wq   = (const float*)d_in[11];
    const float* bq   = (const float*)d_in[12];
    const float* Wv   = (const float*)d_in[13];
    const float* bv   = (const float*)d_in[14];
    const float* Wa   = (const float*)d_in[15];
    const float* ba   = (const float*)d_in[16];
    const float* skip = (const float*)d_in[17];
    const float* arel = (const float*)d_in[18];
    const float* mrel = (const float*)d_in[19];
    const float* prior= (const float*)d_in[20];

    char* ws = (char*)d_ws;
    size_t off = 0;
    auto allocB = [&](size_t bytes) { void* p = ws + off; off += (bytes + 15) & ~15ull; return p; };
    auto allocF = [&](size_t n) { return (float*)allocB(n * 4); };
    auto allocI = [&](size_t n) { return (int*)allocB(n * 4); };
    auto allocS = [&](size_t n) { return (short*)allocB(n * 2); };
    auto allocU = [&](size_t n) { return (unsigned short*)allocB(n * 2); };

    unsigned short* h1b  = allocU((size_t)N1c * 128);
    unsigned short* h2b  = allocU((size_t)N2c * 128);
    unsigned short* Qb1  = allocU((size_t)N1c * 128);
    unsigned short* Qb2  = allocU((size_t)N2c * 128);
    unsigned char*  KV81 = (unsigned char*)allocB((size_t)N1c * 256);
    unsigned char*  KV82 = (unsigned char*)allocB((size_t)N2c * 256);
    unsigned short* agg1 = allocU((size_t)N1c * 128);
    unsigned short* agg2 = allocU((size_t)N2c * 128);
    unsigned short* Emb  = allocU((size_t)N1c * 256);
    unsigned short* Edb  = allocU((size_t)N2c * 256);
    float* bqkv  = allocF(4 * 384);
    short* Wqkvt = allocS(4 * 384 * 128);
    short* Wint1 = allocS(128 * 256);
    short* Wint2 = allocS(128 * 256);
    short* Wat   = allocS(4 * 128 * 128);
    int* rp12  = allocI(N2c + 1);
    int* rp21  = allocI(N1c + 1);
    int* rpm   = allocI(N1c + 1);
    int* es12  = allocI(Ec);
    int* es21  = allocI(Ec);
    int* ps    = allocI(Pc);
    int* gcnt  = allocI(3 * NPART);
    unsigned int* stg12 = (unsigned int*)allocB((size_t)NPART * CAPE * 4);
    unsigned int* stg21 = (unsigned int*)allocB((size_t)NPART * CAPE * 4);
    unsigned int* stgm  = (unsigned int*)allocB((size_t)NPART * CAPP * 4);

    prep_kernel<<<1280, 256, 0, stream>>>(
        Wq, bq, Wk, bk, Wv, bv, arel, mrel, prior,
        Win1, Win2, Wa, Wqkvt, bqkv, Wint1, Wint2, Wat, gcnt);

    scatter_bins_kernel<<<dim3(NBLK, 3), 256, 0, stream>>>(
        ei12, ei21, eidx, gcnt, stg12, stg21, stgm);
    build_csr_kernel<<<dim3(NPART, 3), 256, 0, stream>>>(
        gcnt, stg12, stg21, stgm, rp12, rp21, rpm, es12, es21, ps);

    const int MB = (N1c + 63) / 64;   // 157
    // input projections (relu): fp32 A, K=256 -> bf16 h
    gemm_mfma<0, 1, 0, 0, 0, 256><<<dim3(MB, 2, 2), 256, 0, stream>>>(
        x1, x2, F_INc, Wint1, Wint2, bin1, bin2, h1b, h2b, 128,
        nullptr, nullptr,
        N1c, nullptr, nullptr, nullptr, nullptr, 0);

    for (int l = 0; l < Lc; l++) {
        const unsigned short* A1 = (l == 0) ? h1b : Emb;  int ld1 = (l == 0) ? 128 : 256;
        const unsigned short* A2 = (l == 0) ? h2b : Edb;
        int lt0 = l * 2 + 0, lt1 = l * 2 + 1;
        // fused QKV projections: Q bf16, interleaved fp8 KV
        gemm_mfma<0, 0, 0, 1, 1, 128><<<dim3(MB, 6, 2), 256, 0, stream>>>(
            A1, A2, ld1,
            Wqkvt + (size_t)lt0 * 49152, Wqkvt + (size_t)lt1 * 49152,
            bqkv + lt0 * 384, bqkv + lt1 * 384,
            Qb1, Qb2, 128,
            KV81, KV82,
            N1c, nullptr, nullptr, nullptr, nullptr, 0);
        // both attends, one dispatch (2500 blocks)
        attend_kernel<<<(N1c + N2c) / 8, 128, 0, stream>>>(
            Qb1, KV81, Qb2, KV82, rp12, es12, rp21, es21, agg1, agg2);
        // output GEMMs (gelu on bf16 A, skip blend vs bf16 Hold) into concat buffers
        gemm_mfma<1, 0, 1, 0, 1, 128><<<dim3(MB, 2, 2), 256, 0, stream>>>(
            agg1, agg2, 128,
            Wat + (size_t)lt0 * 16384, Wat + (size_t)lt1 * 16384,
            ba + lt0 * 128, ba + lt1 * 128,
            Emb + l * 128, Edb + l * 128, 256,
            nullptr, nullptr,
            N1c,
            skip + lt0, skip + lt1,
            A1, A2, ld1);
    }

    pred_kernel<<<N1c / 4, 256, 0, stream>>>(Emb, Edb, eidx, rpm, ps, (float*)d_out);
}

// Round 17
// 290.575 us; speedup vs baseline: 1.0727x; 1.0479x over previous
//
#include <hip/hip_runtime.h>
#include <math.h>

#define N1c 10000
#define N2c 10000
#define F_INc 256
#define Ec 480000
#define Pc 200000
#define Lc 2
#define NPART 32
#define NPc 313    // ceil(10000/32)
#define NBLK 256   // chunks per edge structure
#define CAPE 17408 // per-partition staging capacity, edges
#define CAPP 7936  // per-partition staging capacity, pairs

using short8 = __attribute__((ext_vector_type(8))) short;
using float4v = __attribute__((ext_vector_type(4))) float;
using floatx2 = __attribute__((ext_vector_type(2))) float;

__device__ __forceinline__ float gelu_f(float x) {
    const float k0 = 0.7978845608028654f;
    const float k1 = 0.044715f;
    float x3 = x * x * x;
    float t = tanhf(k0 * (x + k1 * x3));
    return 0.5f * x * (1.0f + t);
}

__device__ __forceinline__ float bf2f(unsigned short x) {
    union { unsigned int u; float f; } c;
    c.u = ((unsigned int)x) << 16;
    return c.f;
}
__device__ __forceinline__ unsigned short f2bf(float f) {
    union { float f; unsigned int u; } c;
    c.f = f;
    unsigned int u = c.u;
    unsigned int r = (u + 0x7FFFu + ((u >> 16) & 1u)) >> 16;
    return (unsigned short)r;
}
__device__ __forceinline__ unsigned char f2fp8(float v) {
    unsigned int p = __builtin_amdgcn_cvt_pk_fp8_f32(v, v, 0u, false);
    return (unsigned char)(p & 0xFF);
}

// ---------------- merged weight prep (also zeroes gcnt) ----------------
__global__ __launch_bounds__(256) void prep_kernel(
    const float* __restrict__ Wq, const float* __restrict__ bq,
    const float* __restrict__ Wk, const float* __restrict__ bk,
    const float* __restrict__ Wv, const float* __restrict__ bv,
    const float* __restrict__ arel, const float* __restrict__ mrel,
    const float* __restrict__ prior,
    const float* __restrict__ Win1, const float* __restrict__ Win2,
    const float* __restrict__ Wa,
    short* __restrict__ Wqkvt, float* __restrict__ bqkv,
    short* __restrict__ Wint1, short* __restrict__ Wint2, short* __restrict__ Wat,
    int* __restrict__ gcnt)
{
    if (blockIdx.x == 0 && threadIdx.x < 3 * NPART) gcnt[threadIdx.x] = 0;
    int id = blockIdx.x * 256 + threadIdx.x;
    if (id < 196608) {
        int lt = id / 49152;
        int r = id - lt * 49152;
        int col = r >> 7, c = r & 127;
        short* Wout = Wqkvt + (size_t)lt * 384 * 128;
        float* bout = bqkv + lt * 384;
        if (col < 128) {
            Wout[col * 128 + c] = (short)f2bf(Wq[lt * 16384 + c * 128 + col]);
            if (c == 0) bout[col] = bq[lt * 128 + col];
            return;
        }
        int which = (col < 256) ? 0 : 1;
        int he = col - (which ? 256 : 128);
        int h = he >> 4, e = he & 15;
        const float* W = (which == 0 ? Wk : Wv) + lt * 16384;
        const float* b = (which == 0 ? bk : bv) + lt * 128;
        const float* R = (which == 0 ? arel : mrel) + lt * 2048;
        float sc = (which == 0) ? prior[lt * 8 + h] * 0.25f : 1.0f;
        float acc = 0.f;
        #pragma unroll
        for (int d = 0; d < 16; d++)
            acc += W[c * 128 + h * 16 + d] * R[(h * 16 + d) * 16 + e];
        Wout[col * 128 + c] = (short)f2bf(acc * sc);
        if (c == 0) {
            float bacc = 0.f;
            #pragma unroll
            for (int d = 0; d < 16; d++)
                bacc += b[h * 16 + d] * R[(h * 16 + d) * 16 + e];
            bout[col] = bacc * sc;
        }
    } else {
        int wid = id - 196608;
        if (wid < 65536) {
            int y = wid >> 15;
            int id2 = wid & 32767;
            int n = id2 >> 8, k = id2 & 255;
            const float* W = y ? Win2 : Win1;
            short* O = y ? Wint2 : Wint1;
            O[n * 256 + k] = (short)f2bf(W[k * 128 + n]);
        } else {
            int wid2 = wid - 65536;
            int lt = wid2 >> 14;
            int id2 = wid2 & 16383;
            int n = id2 >> 7, k = id2 & 127;
            Wat[lt * 16384 + n * 128 + k] = (short)f2bf(Wa[lt * 16384 + k * 128 + n]);
        }
    }
}

// ---------------- CSR device bodies ----------------
__device__ void dev_scatter_bins(
    int blk, int z, int* smem,
    const int* __restrict__ ei12, const int* __restrict__ ei21, const int* __restrict__ eidx,
    int* __restrict__ gcnt,
    unsigned int* __restrict__ stg12, unsigned int* __restrict__ stg21,
    unsigned int* __restrict__ stgm)
{
    int t = threadIdx.x;
    const int* key; const int* pay; int E; unsigned int* stg; int cap;
    if (z == 0)      { key = ei12 + Ec; pay = ei12; E = Ec; stg = stg12; cap = CAPE; }
    else if (z == 1) { key = ei21 + Ec; pay = ei21; E = Ec; stg = stg21; cap = CAPE; }
    else             { key = eidx;      pay = nullptr; E = Pc; stg = stgm; cap = CAPP; }
    int chunk = (E + NBLK - 1) / NBLK;
    int start = blk * chunk;
    int stop = min(start + chunk, E);
    int* cnt = smem;
    int* base = smem + NPART;
    int* fill = smem + 2 * NPART;
    if (t < NPART) cnt[t] = 0;
    __syncthreads();
    for (int e = start + t; e < stop; e += 256)
        atomicAdd(&cnt[key[e] / NPc], 1);
    __syncthreads();
    if (t < NPART) {
        base[t] = cnt[t] ? atomicAdd(&gcnt[z * NPART + t], cnt[t]) : 0;
        fill[t] = 0;
    }
    __syncthreads();
    for (int e = start + t; e < stop; e += 256) {
        unsigned int k = (unsigned int)key[e];
        int p = (int)(k / NPc);
        int r = atomicAdd(&fill[p], 1);
        unsigned int pk = (z == 2) ? ((k << 18) | (unsigned int)e)
                                   : ((k << 14) | (unsigned int)pay[e]);
        stg[(size_t)p * cap + base[p] + r] = pk;
    }
}

__device__ void dev_build_csr(
    int p, int z, int* hist, int* fill,
    const int* __restrict__ gcnt,
    const unsigned int* __restrict__ stg12, const unsigned int* __restrict__ stg21,
    const unsigned int* __restrict__ stgm,
    int* __restrict__ rp12, int* __restrict__ rp21, int* __restrict__ rpm,
    int* __restrict__ es12, int* __restrict__ es21, int* __restrict__ ps)
{
    int t = threadIdx.x;
    const unsigned int* stg; int* rowptr; int* out; int cap;
    if (z == 0)      { stg = stg12; rowptr = rp12; out = es12; cap = CAPE; }
    else if (z == 1) { stg = stg21; rowptr = rp21; out = es21; cap = CAPE; }
    else             { stg = stgm;  rowptr = rpm;  out = ps;   cap = CAPP; }
    int ksh = (z == 2) ? 18 : 14;
    unsigned int pmask = (z == 2) ? 0x3FFFFu : 0x3FFFu;
    int baseOut = 0, cntP = 0;
    #pragma unroll
    for (int j = 0; j < NPART; j++) {
        int c = gcnt[z * NPART + j];
        if (j < p) baseOut += c;
        if (j == p) cntP = c;
    }
    const unsigned int* sbase = stg + (size_t)p * cap;
    int lo = p * NPc;
    int hi = min(lo + NPc, 10000);

    hist[t] = 0; hist[t + 256] = 0;
    __syncthreads();
    for (int i = t; i < cntP; i += 256)
        atomicAdd(&hist[(int)(sbase[i] >> ksh) - lo], 1);
    __syncthreads();
    for (int off = 1; off < 512; off <<= 1) {
        int i0 = t, i1 = t + 256;
        int v0 = (i0 >= off) ? hist[i0 - off] : 0;
        int v1 = (i1 >= off) ? hist[i1 - off] : 0;
        __syncthreads();
        hist[i0] += v0; hist[i1] += v1;
        __syncthreads();
    }
    for (int i = t; i < NPc; i += 256) {
        int excl = i ? hist[i - 1] : 0;
        fill[i] = excl;
        if (lo + i < hi) rowptr[lo + i] = baseOut + excl;
    }
    if (p == NPART - 1 && t == 0) rowptr[10000] = baseOut + cntP;
    __syncthreads();
    for (int i = t; i < cntP; i += 256) {
        unsigned int pk = sbase[i];
        int r = atomicAdd(&fill[(int)(pk >> ksh) - lo], 1);
        out[baseOut + r] = (int)(pk & pmask);
    }
}

// ---------------- bf16 MFMA GEMM device body: 64x64 tile, 4 waves, 16x16x32 ----------------
template<int A_GELU, int OUT_RELU, int SKIP, int PACKQKV, int ABF, int KT>
__device__ void dev_gemm(
    int mb, int ny, int z, short* Alds, short* Blds,
    const void* __restrict__ A0v, const void* __restrict__ A1v, int ldA,
    const short* __restrict__ Wt0, const short* __restrict__ Wt1,
    const float* __restrict__ b0, const float* __restrict__ b1,
    unsigned short* __restrict__ C0, unsigned short* __restrict__ C1, int ldC,
    unsigned char* __restrict__ KV8o0, unsigned char* __restrict__ KV8o1,
    int M,
    const float* __restrict__ sk0, const float* __restrict__ sk1,
    const unsigned short* __restrict__ H0, const unsigned short* __restrict__ H1, int ldH)
{
    const void* Av = z ? A1v : A0v;
    const short* Wt = z ? Wt1 : Wt0;
    const float* bias = z ? b1 : b0;
    unsigned short* C = z ? C1 : C0;
    unsigned char* KV8o = z ? KV8o1 : KV8o0;
    const float* skipv = z ? sk1 : sk0;
    const unsigned short* Hold = z ? H1 : H0;

    int tid = threadIdx.x;
    int w = tid >> 6;
    int l = tid & 63;
    int mBase = mb * 64;
    int nBase = ny * 64;

    int srow = tid >> 2;
    int koct = tid & 3;

    float4v acc[4];
    #pragma unroll
    for (int i = 0; i < 4; i++) acc[i] = (float4v){0.f, 0.f, 0.f, 0.f};

    int arow = mBase + srow;
    const short* Wptr = Wt + (size_t)(nBase + srow) * KT + koct * 8;

    int fl = l & 15;
    int fo = (l >> 4) * 8;

    #pragma unroll
    for (int k0 = 0; k0 < KT; k0 += 32) {
        uint4 raw;
        if (ABF) {
            const unsigned short* Ab = (const unsigned short*)Av;
            raw = make_uint4(0u, 0u, 0u, 0u);
            if (arow < M) raw = *(const uint4*)(Ab + (size_t)arow * ldA + k0 + koct * 8);
            if (A_GELU) {
                unsigned int wd[4] = {raw.x, raw.y, raw.z, raw.w};
                #pragma unroll
                for (int i = 0; i < 4; i++) {
                    float lo = gelu_f(bf2f((unsigned short)(wd[i] & 0xFFFFu)));
                    float hi = gelu_f(bf2f((unsigned short)(wd[i] >> 16)));
                    wd[i] = (unsigned int)f2bf(lo) | ((unsigned int)f2bf(hi) << 16);
                }
                raw = make_uint4(wd[0], wd[1], wd[2], wd[3]);
            }
        } else {
            const float* Af = (const float*)Av;
            float av[8];
            if (arow < M) {
                const float4* p = (const float4*)(Af + (size_t)arow * ldA + k0 + koct * 8);
                float4 f0 = p[0], f1 = p[1];
                av[0]=f0.x; av[1]=f0.y; av[2]=f0.z; av[3]=f0.w;
                av[4]=f1.x; av[5]=f1.y; av[6]=f1.z; av[7]=f1.w;
            } else {
                #pragma unroll
                for (int i = 0; i < 8; i++) av[i] = 0.f;
            }
            unsigned int pk[4];
            #pragma unroll
            for (int i = 0; i < 4; i++)
                pk[i] = (unsigned int)f2bf(av[2*i]) | ((unsigned int)f2bf(av[2*i+1]) << 16);
            raw = make_uint4(pk[0], pk[1], pk[2], pk[3]);
        }
        *(uint4*)&Alds[srow * 40 + koct * 8] = raw;
        *(uint4*)&Blds[srow * 40 + koct * 8] = *(const uint4*)(Wptr + k0);
        __syncthreads();

        short8 bfr = *(const short8*)&Blds[(w * 16 + fl) * 40 + fo];
        #pragma unroll
        for (int msub = 0; msub < 4; msub++) {
            short8 afr = *(const short8*)&Alds[(msub * 16 + fl) * 40 + fo];
            acc[msub] = __builtin_amdgcn_mfma_f32_16x16x32_bf16(afr, bfr, acc[msub], 0, 0, 0);
        }
        __syncthreads();
    }

    float sig = 0.f;
    if (SKIP) sig = 1.f / (1.f + __expf(-skipv[0]));
    int col = nBase + w * 16 + fl;
    float bcol = bias[col];
    int rbase = mBase + ((l >> 4) * 4);
    #pragma unroll
    for (int msub = 0; msub < 4; msub++) {
        #pragma unroll
        for (int r = 0; r < 4; r++) {
            int row = rbase + msub * 16 + r;
            if (row >= M) continue;
            float v = acc[msub][r] + bcol;
            if (OUT_RELU) v = fmaxf(v, 0.f);
            if (SKIP) v = sig * v + (1.f - sig) * bf2f(Hold[(size_t)row * ldH + col]);
            if (PACKQKV) {
                if (col < 128) {
                    C[(size_t)row * ldC + col] = f2bf(v);
                } else if (col < 256) {
                    int c = col - 128;
                    KV8o[(size_t)row * 256 + (c >> 3) * 16 + (c & 7)] = f2fp8(v);
                } else {
                    int c = col - 256;
                    KV8o[(size_t)row * 256 + (c >> 3) * 16 + 8 + (c & 7)] = f2fp8(v);
                }
            } else {
                C[(size_t)row * ldC + col] = f2bf(v);
            }
        }
    }
}

// ---------------- standalone GEMM kernel (out GEMMs, layer-1 QKV) ----------------
template<int A_GELU, int OUT_RELU, int SKIP, int PACKQKV, int ABF, int KT>
__global__ __launch_bounds__(256) void gemm_mfma(
    const void* __restrict__ A0v, const void* __restrict__ A1v, int ldA,
    const short* __restrict__ Wt0, const short* __restrict__ Wt1,
    const float* __restrict__ b0, const float* __restrict__ b1,
    unsigned short* __restrict__ C0, unsigned short* __restrict__ C1, int ldC,
    unsigned char* __restrict__ KV8o0, unsigned char* __restrict__ KV8o1,
    int M,
    const float* __restrict__ sk0, const float* __restrict__ sk1,
    const unsigned short* __restrict__ H0, const unsigned short* __restrict__ H1, int ldH)
{
    __shared__ short Alds[64 * 40];
    __shared__ short Blds[64 * 40];
    dev_gemm<A_GELU, OUT_RELU, SKIP, PACKQKV, ABF, KT>(
        blockIdx.x, blockIdx.y, blockIdx.z, Alds, Blds,
        A0v, A1v, ldA, Wt0, Wt1, b0, b1, C0, C1, ldC,
        KV8o0, KV8o1, M, sk0, sk1, H0, H1, ldH);
}

// ---------------- combo2: scatter_bins (768 blocks first) + input-proj GEMM (628) ---------
__global__ __launch_bounds__(256) void combo2_kernel(
    const int* __restrict__ ei12, const int* __restrict__ ei21, const int* __restrict__ eidx,
    int* __restrict__ gcnt,
    unsigned int* __restrict__ stg12, unsigned int* __restrict__ stg21,
    unsigned int* __restrict__ stgm,
    const float* __restrict__ x1, const float* __restrict__ x2,
    const short* __restrict__ Wint1, const short* __restrict__ Wint2,
    const float* __restrict__ bin1, const float* __restrict__ bin2,
    unsigned short* __restrict__ h1b, unsigned short* __restrict__ h2b)
{
    __shared__ short Alds[64 * 40];
    __shared__ short Blds[64 * 40];
    int bx = blockIdx.x;
    if (bx < 768) {
        dev_scatter_bins(bx & 255, bx >> 8, (int*)Alds,
                         ei12, ei21, eidx, gcnt, stg12, stg21, stgm);
    } else {
        int idx = bx - 768;          // 628 = 157 * 4
        int mb = idx % 157;
        int r = idx / 157;           // 0..3: ny = r&1, z = r>>1
        dev_gemm<0, 1, 0, 0, 0, 256>(
            mb, r & 1, r >> 1, Alds, Blds,
            x1, x2, F_INc, Wint1, Wint2, bin1, bin2,
            h1b, h2b, 128, nullptr, nullptr,
            N1c, nullptr, nullptr, nullptr, nullptr, 0);
    }
}

// ---------------- combo3: build_csr (96 blocks first) + layer-0 QKV GEMM (1884) ----------
__global__ __launch_bounds__(256) void combo3_kernel(
    const int* __restrict__ gcnt,
    const unsigned int* __restrict__ stg12, const unsigned int* __restrict__ stg21,
    const unsigned int* __restrict__ stgm,
    int* __restrict__ rp12, int* __restrict__ rp21, int* __restrict__ rpm,
    int* __restrict__ es12, int* __restrict__ es21, int* __restrict__ ps,
    const unsigned short* __restrict__ h1b, const unsigned short* __restrict__ h2b,
    const short* __restrict__ Wqkvt0, const short* __restrict__ Wqkvt1,
    const float* __restrict__ bqkv0, const float* __restrict__ bqkv1,
    unsigned short* __restrict__ Qb1, unsigned short* __restrict__ Qb2,
    unsigned char* __restrict__ KV81, unsigned char* __restrict__ KV82)
{
    __shared__ short Alds[64 * 40];
    __shared__ short Blds[64 * 40];
    int bx = blockIdx.x;
    if (bx < 96) {
        dev_build_csr(bx & 31, bx >> 5, (int*)Alds, (int*)Blds,
                      gcnt, stg12, stg21, stgm,
                      rp12, rp21, rpm, es12, es21, ps);
    } else {
        int idx = bx - 96;           // 1884 = 157 * 12
        int mb = idx % 157;
        int r = idx / 157;           // 0..11: ny = r%6, z = r/6
        dev_gemm<0, 0, 0, 1, 1, 128>(
            mb, r % 6, r / 6, Alds, Blds,
            h1b, h2b, 128, Wqkvt0, Wqkvt1, bqkv0, bqkv1,
            Qb1, Qb2, 128, KV81, KV82,
            N1c, nullptr, nullptr, nullptr, nullptr, 0);
    }
}

// ---------------- attend: both directions, one dispatch; 1 uint4 load/edge/lane ----------
__global__ __launch_bounds__(128) void attend_kernel(
    const unsigned short* __restrict__ Qb1, const unsigned char* __restrict__ KV81,
    const unsigned short* __restrict__ Qb2, const unsigned char* __restrict__ KV82,
    const int* __restrict__ rp12, const int* __restrict__ es12,
    const int* __restrict__ rp21, const int* __restrict__ es21,
    unsigned short* __restrict__ agg1, unsigned short* __restrict__ agg2)
{
    int b = blockIdx.x;
    const unsigned short* Qb; const unsigned char* KV; const int* rp; const int* es;
    unsigned short* outb; int n;
    if (b < 1250) { n = b * 8 + (threadIdx.x >> 4);          Qb = Qb2; KV = KV81; rp = rp12; es = es12; outb = agg2; }
    else          { n = (b - 1250) * 8 + (threadIdx.x >> 4); Qb = Qb1; KV = KV82; rp = rp21; es = es21; outb = agg1; }
    int ln = threadIdx.x & 15;

    float q[8];
    {
        const ushort4* qp = (const ushort4*)(Qb + (size_t)n * 128 + 8 * ln);
        ushort4 qa = qp[0], qc = qp[1];
        q[0]=bf2f(qa.x); q[1]=bf2f(qa.y); q[2]=bf2f(qa.z); q[3]=bf2f(qa.w);
        q[4]=bf2f(qc.x); q[5]=bf2f(qc.y); q[6]=bf2f(qc.z); q[7]=bf2f(qc.w);
    }
    int beg = rp[n], end = rp[n + 1];
    float s = 0.f;
    float acc[8];
    #pragma unroll
    for (int c = 0; c < 8; c++) acc[c] = 0.f;

    auto dec8 = [&](unsigned int w0, unsigned int w1, float* d) {
        floatx2 a0 = __builtin_amdgcn_cvt_pk_f32_fp8(w0, false);
        floatx2 a1 = __builtin_amdgcn_cvt_pk_f32_fp8(w0, true);
        floatx2 a2 = __builtin_amdgcn_cvt_pk_f32_fp8(w1, false);
        floatx2 a3 = __builtin_amdgcn_cvt_pk_f32_fp8(w1, true);
        d[0]=a0[0]; d[1]=a0[1]; d[2]=a1[0]; d[3]=a1[1];
        d[4]=a2[0]; d[5]=a2[1]; d[6]=a3[0]; d[7]=a3[1];
    };
    auto proc1 = [&](uint4 kv) {
        float kd[8], vd[8];
        dec8(kv.x, kv.y, kd);
        float p = q[0]*kd[0] + q[1]*kd[1] + q[2]*kd[2] + q[3]*kd[3]
                + q[4]*kd[4] + q[5]*kd[5] + q[6]*kd[6] + q[7]*kd[7];
        p += __shfl_xor(p, 1, 2);
        float x = __expf(p);
        s += x;
        dec8(kv.z, kv.w, vd);
        #pragma unroll
        for (int c = 0; c < 8; c++) acc[c] += x * vd[c];
    };
    auto ld = [&](int e) { return *(const uint4*)(KV + (size_t)e * 256 + 16 * ln); };

    int i = beg;
    int pre = min(end, (beg + 3) & ~3);
    for (; i < pre; i++) proc1(ld(es[i]));
    for (; i + 8 <= end; i += 8) {
        int4 ea = *(const int4*)&es[i];
        int4 eb = *(const int4*)&es[i + 4];
        uint4 w0 = ld(ea.x), w1 = ld(ea.y), w2 = ld(ea.z), w3 = ld(ea.w);
        uint4 w4 = ld(eb.x), w5 = ld(eb.y), w6 = ld(eb.z), w7 = ld(eb.w);
        proc1(w0); proc1(w1); proc1(w2); proc1(w3);
        proc1(w4); proc1(w5); proc1(w6); proc1(w7);
    }
    for (; i + 4 <= end; i += 4) {
        int4 ea = *(const int4*)&es[i];
        uint4 w0 = ld(ea.x), w1 = ld(ea.y), w2 = ld(ea.z), w3 = ld(ea.w);
        proc1(w0); proc1(w1); proc1(w2); proc1(w3);
    }
    for (; i < end; i++) proc1(ld(es[i]));

    float inv = 1.f / (s + 1e-16f);
    unsigned int w0 = (unsigned int)f2bf(acc[0]*inv) | ((unsigned int)f2bf(acc[1]*inv) << 16);
    unsigned int w1 = (unsigned int)f2bf(acc[2]*inv) | ((unsigned int)f2bf(acc[3]*inv) << 16);
    unsigned int w2 = (unsigned int)f2bf(acc[4]*inv) | ((unsigned int)f2bf(acc[5]*inv) << 16);
    unsigned int w3 = (unsigned int)f2bf(acc[6]*inv) | ((unsigned int)f2bf(acc[7]*inv) << 16);
    *(uint4*)(outb + (size_t)n * 128 + 8 * ln) = make_uint4(w0, w1, w2, w3);
}

// ---------------- pred: 4 m/block, 4 pair-groups of 16 lanes per wave ----------------
__global__ __launch_bounds__(256) void pred_kernel(
    const unsigned short* __restrict__ Emb, const unsigned short* __restrict__ Edb,
    const int* __restrict__ eidx,
    const int* __restrict__ rpm, const int* __restrict__ porder,
    float* __restrict__ out)
{
    int m = blockIdx.x * 4 + (threadIdx.x >> 6);
    int l = threadIdx.x & 63;
    int g = l >> 4;
    int ln = l & 15;
    int beg = rpm[m], end = rpm[m + 1];
    if (beg == end) return;
    float a[16];
    {
        const uint4* ap = (const uint4*)(Emb + (size_t)m * 256 + 16 * ln);
        uint4 u0 = ap[0], u1 = ap[1];
        unsigned int wv[8] = {u0.x, u0.y, u0.z, u0.w, u1.x, u1.y, u1.z, u1.w};
        #pragma unroll
        for (int i = 0; i < 8; i++) {
            a[2*i]   = bf2f((unsigned short)(wv[i] & 0xFFFFu));
            a[2*i+1] = bf2f((unsigned short)(wv[i] >> 16));
        }
    }
    for (int i = beg + g; i < end; i += 4) {
        int p = porder[i];
        int d = eidx[Pc + p];
        const uint4* bp = (const uint4*)(Edb + (size_t)d * 256 + 16 * ln);
        uint4 u0 = bp[0], u1 = bp[1];
        unsigned int wv[8] = {u0.x, u0.y, u0.z, u0.w, u1.x, u1.y, u1.z, u1.w};
        float s = 0.f;
        #pragma unroll
        for (int j = 0; j < 8; j++)
            s += a[2*j] * bf2f((unsigned short)(wv[j] & 0xFFFFu))
               + a[2*j+1] * bf2f((unsigned short)(wv[j] >> 16));
        s += __shfl_xor(s, 1, 16);
        s += __shfl_xor(s, 2, 16);
        s += __shfl_xor(s, 4, 16);
        s += __shfl_xor(s, 8, 16);
        if (ln == 0) out[p] = s;
    }
}

extern "C" void kernel_launch(void* const* d_in, const int* in_sizes, int n_in,
                              void* d_out, int out_size, void* d_ws, size_t ws_size,
                              hipStream_t stream)
{
    const float* x1   = (const float*)d_in[0];
    const float* x2   = (const float*)d_in[1];
    const int*   ei12 = (const int*)d_in[2];
    const int*   ei21 = (const int*)d_in[3];
    const int*   eidx = (const int*)d_in[4];
    const float* Win1 = (const float*)d_in[5];
    const float* bin1 = (const float*)d_in[6];
    const float* Win2 = (const float*)d_in[7];
    const float* bin2 = (const float*)d_in[8];
    const float* Wk   = (const float*)d_in[9];
    const float* bk   = (const float*)d_in[10];
    const float* Wq   = (const float*)d_in[11];
    const float* bq   = (const float*)d_in[12];
    const float* Wv   = (const float*)d_in[13];
    const float* bv   = (const float*)d_in[14];
    const float* Wa   = (const float*)d_in[15];
    const float* ba   = (const float*)d_in[16];
    const float* skip = (const float*)d_in[17];
    const float* arel = (const float*)d_in[18];
    const float* mrel = (const float*)d_in[19];
    const float* prior= (const float*)d_in[20];

    char* ws = (char*)d_ws;
    size_t off = 0;
    auto allocB = [&](size_t bytes) { void* p = ws + off; off += (bytes + 15) & ~15ull; return p; };
    auto allocF = [&](size_t n) { return (float*)allocB(n * 4); };
    auto allocI = [&](size_t n) { return (int*)allocB(n * 4); };
    auto allocS = [&](size_t n) { return (short*)allocB(n * 2); };
    auto allocU = [&](size_t n) { return (unsigned short*)allocB(n * 2); };

    unsigned short* h1b  = allocU((size_t)N1c * 128);
    unsigned short* h2b  = allocU((size_t)N2c * 128);
    unsigned short* Qb1  = allocU((size_t)N1c * 128);
    unsigned short* Qb2  = allocU((size_t)N2c * 128);
    unsigned char*  KV81 = (unsigned char*)allocB((size_t)N1c * 256);
    unsigned char*  KV82 = (unsigned char*)allocB((size_t)N2c * 256);
    unsigned short* agg1 = allocU((size_t)N1c * 128);
    unsigned short* agg2 = allocU((size_t)N2c * 128);
    unsigned short* Emb  = allocU((size_t)N1c * 256);
    unsigned short* Edb  = allocU((size_t)N2c * 256);
    float* bqkv  = allocF(4 * 384);
    short* Wqkvt = allocS(4 * 384 * 128);
    short* Wint1 = allocS(128 * 256);
    short* Wint2 = allocS(128 * 256);
    short* Wat   = allocS(4 * 128 * 128);
    int* rp12  = allocI(N2c + 1);
    int* rp21  = allocI(N1c + 1);
    int* rpm   = allocI(N1c + 1);
    int* es12  = allocI(Ec);
    int* es21  = allocI(Ec);
    int* ps    = allocI(Pc);
    int* gcnt  = allocI(3 * NPART);
    unsigned int* stg12 = (unsigned int*)allocB((size_t)NPART * CAPE * 4);
    unsigned int* stg21 = (unsigned int*)allocB((size_t)NPART * CAPE * 4);
    unsigned int* stgm  = (unsigned int*)allocB((size_t)NPART * CAPP * 4);

    // 1. weight prep (+ gcnt zero)
    prep_kernel<<<1280, 256, 0, stream>>>(
        Wq, bq, Wk, bk, Wv, bv, arel, mrel, prior,
        Win1, Win2, Wa, Wqkvt, bqkv, Wint1, Wint2, Wat, gcnt);

    // 2. scatter_bins + input-proj GEMM (independent; CSR blocks first)
    combo2_kernel<<<768 + 628, 256, 0, stream>>>(
        ei12, ei21, eidx, gcnt, stg12, stg21, stgm,
        x1, x2, Wint1, Wint2, bin1, bin2, h1b, h2b);

    // 3. build_csr + layer-0 QKV GEMM (independent; CSR blocks first)
    combo3_kernel<<<96 + 1884, 256, 0, stream>>>(
        gcnt, stg12, stg21, stgm, rp12, rp21, rpm, es12, es21, ps,
        h1b, h2b,
        Wqkvt + 0 * 49152, Wqkvt + 1 * 49152,
        bqkv + 0 * 384, bqkv + 1 * 384,
        Qb1, Qb2, KV81, KV82);

    // 4. attend layer 0
    attend_kernel<<<(N1c + N2c) / 8, 128, 0, stream>>>(
        Qb1, KV81, Qb2, KV82, rp12, es12, rp21, es21, agg1, agg2);

    // 5. layer-0 out-GEMM -> Em/Ed cols [0,128)
    gemm_mfma<1, 0, 1, 0, 1, 128><<<dim3(157, 2, 2), 256, 0, stream>>>(
        agg1, agg2, 128,
        Wat + 0 * 16384, Wat + 1 * 16384, ba + 0 * 128, ba + 1 * 128,
        Emb, Edb, 256,
        nullptr, nullptr,
        N1c, skip + 0, skip + 1, h1b, h2b, 128);

    // 6. layer-1 QKV GEMM (reads Em/Ed cols [0,128))
    gemm_mfma<0, 0, 0, 1, 1, 128><<<dim3(157, 6, 2), 256, 0, stream>>>(
        Emb, Edb, 256,
        Wqkvt + 2 * 49152, Wqkvt + 3 * 49152,
        bqkv + 2 * 384, bqkv + 3 * 384,
        Qb1, Qb2, 128, KV81, KV82,
        N1c, nullptr, nullptr, nullptr, nullptr, 0);

    // 7. attend layer 1
    attend_kernel<<<(N1c + N2c) / 8, 128, 0, stream>>>(
        Qb1, KV81, Qb2, KV82, rp12, es12, rp21, es21, agg1, agg2);

    // 8. layer-1 out-GEMM -> Em/Ed cols [128,256), skip vs cols [0,128)
    gemm_mfma<1, 0, 1, 0, 1, 128><<<dim3(157, 2, 2), 256, 0, stream>>>(
        agg1, agg2, 128,
        Wat + 2 * 16384, Wat + 3 * 16384, ba + 2 * 128, ba + 3 * 128,
        Emb + 128, Edb + 128, 256,
        nullptr, nullptr,
        N1c, skip + 2, skip + 3, Emb, Edb, 256);

    // 9. pred
    pred_kernel<<<N1c / 4, 256, 0, stream>>>(Emb, Edb, eidx, rpm, ps, (float*)d_out);
}